// Round 12
// baseline (2057.535 us; speedup 1.0000x reference)
//
#include <hip/hip_runtime.h>

#define B 4
#define N 8192
#define F 64
#define S 2048
#define K 16
#define C 128
#define R (B*S*K)   // 131072 rows

typedef float v2f __attribute__((ext_vector_type(2)));

// ---------- exact-arithmetic helpers (match numpy op order, no fma fusion) ----------
__device__ __forceinline__ float norm2f(float x, float y, float z) {
#pragma clang fp contract(off)
  return (x*x + y*y) + z*z;
}

__device__ __forceinline__ float knn_d2(float4 q, float4 p) {
#pragma clang fp contract(off)
  float dot = (q.x*p.x + q.y*p.y) + q.z*p.z;
  return (q.w + p.w) - 2.0f*dot;           // (qn+pn) - 2*dot, reference order
}

// opaque def: forbids rematerialization of the value -> stays in a VGPR
__device__ __forceinline__ void pinf(float& v) { asm volatile("" : "+v"(v)); }

// ---------- DPP cross-lane (VALU pipe). bound_ctrl=1 -> invalid lanes read 0:
// identity-safe for u32/f32 max of non-negative values. HW-verified rounds 2-10.
#define DPP_U(v, ctrl) ((unsigned)__builtin_amdgcn_update_dpp(0, (int)(v), ctrl, 0xf, 0xf, true))
#define DPP_F(v, ctrl) __int_as_float((int)DPP_U(__float_as_uint(v), ctrl))
__device__ __forceinline__ unsigned umaxu(unsigned a, unsigned b) { return a > b ? a : b; }

#define WAVE_MAX_U(x) do { \
  x = umaxu(x, DPP_U(x,0x111)); x = umaxu(x, DPP_U(x,0x112)); \
  x = umaxu(x, DPP_U(x,0x114)); x = umaxu(x, DPP_U(x,0x118)); \
  x = umaxu(x, DPP_U(x,0x142)); x = umaxu(x, DPP_U(x,0x143)); } while(0)

// f32 max across wave into lane 63 (values >= 0; bound_ctrl 0-fill is identity-safe)
#define WAVE_MAX_F(x) do { \
  x = fmaxf(x, DPP_F(x,0x111)); x = fmaxf(x, DPP_F(x,0x112)); \
  x = fmaxf(x, DPP_F(x,0x114)); x = fmaxf(x, DPP_F(x,0x118)); \
  x = fmaxf(x, DPP_F(x,0x142)); x = fmaxf(x, DPP_F(x,0x143)); } while(0)

// ---------- prep: pad xyz to float4 with |p|^2 in w; zero progress counters ----------
__global__ void prep_kernel(const float* __restrict__ xyz, float4* __restrict__ pts4,
                            unsigned* __restrict__ prog) {
  int i = blockIdx.x*blockDim.x + threadIdx.x;   // B*N
  if (i < B) prog[i] = 0u;
  if (i >= B*N) return;
  float x = xyz[i*3+0], y = xyz[i*3+1], z = xyz[i*3+2];
  pts4[i] = make_float4(x, y, z, norm2f(x, y, z));
}

// ---------- transpose w1 [o][c] -> w1t [c][o] for contiguous scalar weight loads ----------
__global__ void transpose_w1_kernel(const float* __restrict__ w1, float* __restrict__ w1t) {
  int i = blockIdx.x*256 + threadIdx.x;    // C*C = 16384
  int o = i >> 7, c = i & 127;
  w1t[c*C + o] = w1[o*C + c];
}

// ---------- transpose w0 [o][67] -> w0t [67][o] for coalesced per-lane weight loads ----------
__global__ void transpose_w0_kernel(const float* __restrict__ w0, float* __restrict__ w0t) {
  int i = blockIdx.x*256 + threadIdx.x;    // 67*128 = 8576
  if (i >= 67*C) return;
  int c = i >> 7, o = i & 127;
  w0t[c*C + o] = w0[o*67 + c];
}

// ---------- FUSED FPS (blocks 0..3) + KNN+GEMM0 (blocks 4..1027, consumers).
// SINGLE VARIABLE vs r8 (the 1982us best): 512 threads (2 waves/SIMD), 16
// points/thread. Evidence: step is latency-bound (~2100cy, only ~600cy issue);
// every 1-wave/SIMD variant lands 870-920 ns/step. 2 waves/SIMD lets one wave's
// dependency stalls hide under the other. r1's 1024t failure was the OLD heavy
// u64-DPP+atomic reduce (big fixed cost x16 waves); the slim reduce (26 instr,
// no atomic) makes the fixed cost small. Tail grows to 8 wave keys
// (4x b128 + 7x f64 max). Argmax = r8's proven 2-chain. Everything else r8. ----------
__global__ __launch_bounds__(512, 1) void fps_knn_kernel(const float4* __restrict__ pts4,
                                                         float4* __restrict__ q4,
                                                         float* __restrict__ out_xyz,
                                                         const float* __restrict__ feat,
                                                         const float* __restrict__ w0t,
                                                         const float* __restrict__ b0,
                                                         float* __restrict__ Z,
                                                         unsigned* __restrict__ prog) {
  __shared__ float4 cw[N];                 // 128 KB point cache (winner lookup, b128 read)
  __shared__ __align__(16) unsigned long long redarr[2][8];  // parity-buffered wave keys

  if (blockIdx.x < B) {
    // ================= FPS role: 512 threads = 8 waves, 2 per SIMD =================
    const int b = blockIdx.x;
    const int t = threadIdx.x;               // 0..511
    const float4* pb = pts4 + b*N;

    // thread t owns points i*512+t, i=0..15, paired (2j, 2j+1); pinned in VGPRs
    v2f px[8], py[8], pz[8], md[8];
#pragma unroll
    for (int j = 0; j < 8; ++j) {
      int i0 = (2*j)*512 + t, i1 = (2*j+1)*512 + t;
      float4 v0 = pb[i0];                  // coalesced
      float4 v1 = pb[i1];
      cw[i0] = v0; cw[i1] = v1;
      pinf(v0.x); pinf(v0.y); pinf(v0.z);
      pinf(v1.x); pinf(v1.y); pinf(v1.z);
      px[j] = (v2f){v0.x, v1.x};
      py[j] = (v2f){v0.y, v1.y};
      pz[j] = (v2f){v0.z, v1.z};
      md[j] = (v2f){1e10f, 1e10f};         // BIG
    }
    __syncthreads();                       // cw visible before use

    float wx, wy, wz;
    { float4 p0 = pb[0]; wx = p0.x; wy = p0.y; wz = p0.z; }  // reference starts at idx 0

    for (int s = 0; ; ++s) {
      if (t == 0) {
        // publish BEFORE this step's store: fence only waits on >=1-step-old stores
        if ((s & 31) == 0 && s) {
          __threadfence();                 // order q4 stores before prog publish
          __hip_atomic_store(prog + b, (unsigned)s, __ATOMIC_RELAXED, __HIP_MEMORY_SCOPE_AGENT);
        }
        float w2 = norm2f(wx, wy, wz);
        q4[b*S + s] = make_float4(wx, wy, wz, w2);
      }
      if (s == S-1) break;

      // packed min_d update + two independent argmax chains (i 0..7 / 8..15).
      // per-element IEEE rounding identical to scalar ((dx*dx+dy*dy)+dz*dz).
      v2f wxx = (v2f){wx, wx}, wyy = (v2f){wy, wy}, wzz = (v2f){wz, wz};
      float bvA = -1.0f, bvB = -1.0f; int biA = 0, biB = 0;
#pragma unroll
      for (int j = 0; j < 8; ++j) {
#pragma clang fp contract(off)
        v2f dx = px[j] - wxx;
        v2f dy = py[j] - wyy;
        v2f dz = pz[j] - wzz;
        v2f d  = (dx*dx + dy*dy) + dz*dz;  // v_pk/scalar sub-mul-add, no fma
        v2f m;
        m.x = fminf(md[j].x, d.x);
        m.y = fminf(md[j].y, d.y);
        md[j] = m;
        if (j < 4) {                       // chain A: i 0..7
          bool g0 = m.x > bvA;  bvA = g0 ? m.x : bvA;  biA = g0 ? (2*j)   : biA;
          bool g1 = m.y > bvA;  bvA = g1 ? m.y : bvA;  biA = g1 ? (2*j+1) : biA;
        } else {                           // chain B: i 8..15
          bool g0 = m.x > bvB;  bvB = g0 ? m.x : bvB;  biB = g0 ? (2*j)   : biB;
          bool g1 = m.y > bvB;  bvB = g1 ? m.y : bvB;  biB = g1 ? (2*j+1) : biB;
        }
      }
      // merge chains: strict > keeps A (lower i = lower global idx) on ties
      bool gB = bvB > bvA;
      float bv = gB ? bvB : bvA;           // bv >= 0 always (set at j=0 / j=4)
      int   bi = gB ? biB : biA;

      // ---- two-stage wave reduce: f32 value max, then min-original-idx among ties
      float v = bv;
      WAVE_MAX_F(v);                       // lane 63 holds wave max value
      float wmaxv = __int_as_float(__builtin_amdgcn_readlane(__float_as_int(v), 63));
      unsigned loi = 8191u - (((unsigned)bi << 9) + (unsigned)t);  // bigger = smaller oi
      unsigned tmp = (bv == wmaxv) ? loi : 0u;
      WAVE_MAX_U(tmp);                     // lane 63: max loi among value-ties
      if ((t & 63) == 63)
        redarr[s & 1][t >> 6] = ((unsigned long long)__float_as_uint(wmaxv) << 32)
                              | (unsigned long long)tmp;
      __syncthreads();                     // single barrier/step; writes ordered by it

      // global best of 8 wave keys: positive u64 patterns order as f64 -> 7x v_max_f64
      const unsigned long long* ra = redarr[s & 1];
      ulonglong2 ka = ((const ulonglong2*)ra)[0];
      ulonglong2 kb = ((const ulonglong2*)ra)[1];
      ulonglong2 kc = ((const ulonglong2*)ra)[2];
      ulonglong2 kd = ((const ulonglong2*)ra)[3];
      double d0 = __longlong_as_double((long long)ka.x);
      double d1 = __longlong_as_double((long long)ka.y);
      double d2 = __longlong_as_double((long long)kb.x);
      double d3 = __longlong_as_double((long long)kb.y);
      double d4 = __longlong_as_double((long long)kc.x);
      double d5 = __longlong_as_double((long long)kc.y);
      double d6 = __longlong_as_double((long long)kd.x);
      double d7 = __longlong_as_double((long long)kd.y);
      double g  = fmax(fmax(fmax(d0, d1), fmax(d2, d3)),
                       fmax(fmax(d4, d5), fmax(d6, d7)));
      unsigned long long gb = (unsigned long long)__double_as_longlong(g);
      int w = 8191 - (int)((unsigned)gb & 0x1FFFu); // winner original index
      float4 pw = cw[w];                   // one same-address ds_read_b128 broadcast
      wx = pw.x; wy = pw.y; wz = pw.z;
    }
    if (t == 0) {                          // final publish covers tail (incl. s=S-1)
      __threadfence();                     // drains all q4 stores (vmcnt 0)
      __hip_atomic_store(prog + b, (unsigned)S, __ATOMIC_RELAXED, __HIP_MEMORY_SCOPE_AGENT);
    }
    __syncthreads();                       // t0's drain done -> q4 fully visible in L2
    // out_xyz write-back off the critical path (q4 is L2-hot)
    for (int i = t; i < S; i += 512) {
      float4 v = q4[b*S + i];
      out_xyz[(b*S + i)*3 + 0] = v.x;
      out_xyz[(b*S + i)*3 + 1] = v.y;
      out_xyz[(b*S + i)*3 + 2] = v.z;
    }
  } else {
    // ================= consumer role: one WAVE per query (KNN + GEMM0), 8 waves/block ==
    const int qw   = (blockIdx.x - B)*8 + (threadIdx.x >> 6);  // 0..B*S-1
    const int lane = threadIdx.x & 63;
    const int b    = qw & 3;               // interleave batches: earliest queries first
    const int s    = qw >> 2;
    const int bs   = b*S + s;
    const float4* pb = pts4 + (size_t)b*N;

    // spin until query s of batch b is published (prog jumps in steps of 32)
    while (__hip_atomic_load(prog + b, __ATOMIC_RELAXED, __HIP_MEMORY_SCOPE_AGENT) <= (unsigned)s)
      __builtin_amdgcn_s_sleep(64);
    __threadfence();                       // acquire: order prog read before q4 read

    float4 q = q4[bs];                     // same addr across wave -> broadcast

    float dv[16]; int di[16];
#pragma unroll
    for (int j = 0; j < 16; ++j) { dv[j] = 3.4e38f; di[j] = 0x7FFFFFFF; }

    // scan: lane owns points n = j*64 + lane (ascending -> within-lane ties keep lower idx)
    for (int j = 0; j < N/64; ++j) {
      int n = j*64 + lane;
      float4 p = pb[n];                    // coalesced global_load_dwordx4
      float d2 = knn_d2(q, p);
#pragma unroll
      for (int k = 15; k >= 1; --k) {
        bool s1 = d2 < dv[k-1];            // strict: incumbent (earlier idx) wins ties
        bool s2 = d2 < dv[k];
        dv[k] = fmaxf(dv[k-1], fminf(d2, dv[k]));   // med3: sorted-insert value update
        di[k] = s1 ? di[k-1] : (s2 ? n : di[k]);
      }
      bool s0 = d2 < dv[0];
      dv[0] = fminf(d2, dv[0]);
      di[0] = s0 ? n : di[0];
    }

    // merge: 16 extraction rounds over the 64 sorted lane-lists
    int myg = 0;
#pragma unroll 1
    for (int r = 0; r < 16; ++r) {
      unsigned bits = __float_as_uint(dv[0]);
      unsigned ord  = bits ^ (0x80000000u | (unsigned)(((int)bits) >> 31));
      unsigned mk   = ~ord;                // max(mk) == min distance (total order)
      unsigned m = mk;
      WAVE_MAX_U(m);
      unsigned wm = (unsigned)__builtin_amdgcn_readlane((int)m, 63);
      unsigned ci = (mk == wm) ? ~(unsigned)di[0] : 0u;
      unsigned m2 = ci;
      WAVE_MAX_U(m2);
      unsigned wi = (unsigned)__builtin_amdgcn_readlane((int)m2, 63);
      int g = (int)~wi;                    // winning global point index
      if (lane == r) myg = g;
      bool win = (mk == wm) && ((unsigned)di[0] == ~wi);
#pragma unroll
      for (int k = 0; k < 15; ++k) {
        dv[k] = win ? dv[k+1] : dv[k];
        di[k] = win ? di[k+1] : di[k];
      }
      dv[15] = win ? 3.4e38f    : dv[15];
      di[15] = win ? 0x7FFFFFFF : di[15];
    }

    // ---- fused GEMM0: this wave computes its query's 16 rows of Z.
    // lane owns outputs o0 and o0+64; per output: b0-init + ascending-c fmaf
    // (bit-identical accumulation order to the old gemm0 kernel).
    const int o0 = lane;
    const float bb0 = b0[o0];              // coalesced
    const float bb1 = b0[o0 + 64];
    const float* w0c = w0t + o0;           // w0t[c*C + o]
    float* zb = Z + (size_t)bs*K*C;
#pragma unroll 1
    for (int k = 0; k < K; ++k) {
      int p = __builtin_amdgcn_readlane(myg, k);   // neighbor id (uniform)
      float4 pp = pts4[(size_t)b*N + p];           // uniform addr -> broadcast
      float a0 = bb0, a1 = bb1;
      float x0 = pp.x - q.x, x1 = pp.y - q.y, x2 = pp.z - q.z;
      a0 = fmaf(x0, w0c[0*C],      a0); a1 = fmaf(x0, w0c[0*C + 64], a1);
      a0 = fmaf(x1, w0c[1*C],      a0); a1 = fmaf(x1, w0c[1*C + 64], a1);
      a0 = fmaf(x2, w0c[2*C],      a0); a1 = fmaf(x2, w0c[2*C + 64], a1);
      const float4* fp = (const float4*)(feat + ((size_t)b*N + p)*F);
#pragma unroll
      for (int i = 0; i < 16; ++i) {
        float4 vv = fp[i];                 // uniform addr -> broadcast
        const float* wc = w0c + (3 + 4*i)*C;
        a0 = fmaf(vv.x, wc[0*C], a0); a1 = fmaf(vv.x, wc[0*C + 64], a1);
        a0 = fmaf(vv.y, wc[1*C], a0); a1 = fmaf(vv.y, wc[1*C + 64], a1);
        a0 = fmaf(vv.z, wc[2*C], a0); a1 = fmaf(vv.z, wc[2*C + 64], a1);
        a0 = fmaf(vv.w, wc[3*C], a0); a1 = fmaf(vv.w, wc[3*C + 64], a1);
      }
      zb[k*C + o0]      = a0;              // coalesced
      zb[k*C + o0 + 64] = a1;
    }
  }
}

// ---------- per-channel stats partials: sum and sumsq over rows ----------
__global__ void stats_kernel(const float* __restrict__ Z, float* __restrict__ part) {
  int c = threadIdx.x & 127;
  int g = threadIdx.x >> 7;                // 0/1
  int chunk = blockIdx.x*2 + g;            // 0..255
  const int rows = R/256;                  // 512
  const float* zp = Z + (size_t)chunk*rows*C + c;
  float s1 = 0.f, s2 = 0.f;
  for (int j = 0; j < rows; ++j) {
    float v = zp[(size_t)j*C];
    s1 += v;
    s2 = fmaf(v, v, s2);
  }
  __shared__ float sh[2][2][128];
  sh[g][0][c] = s1; sh[g][1][c] = s2;
  __syncthreads();
  if (g == 0) {
    part[(blockIdx.x*128 + c)*2 + 0] = s1 + sh[1][0][c];
    part[(blockIdx.x*128 + c)*2 + 1] = s2 + sh[1][1][c];
  }
}

// ---------- finalize BN: A = gamma*rstd, B = beta - mean*gamma*rstd ----------
__global__ void finalize_kernel(const float* __restrict__ part,
                                const float* __restrict__ gamma,
                                const float* __restrict__ beta,
                                float* __restrict__ AB) {
  int c = threadIdx.x;                     // 128 threads
  float s1 = 0.f, s2 = 0.f;
  for (int i = 0; i < 128; ++i) {
    s1 += part[(i*128 + c)*2 + 0];
    s2 += part[(i*128 + c)*2 + 1];
  }
  const float inv = 1.0f/(float)R;
  float mean = s1*inv;
  float var  = s2*inv - mean*mean;         // biased variance
  float rstd = rsqrtf(var + 1e-5f);
  float a = gamma[c]*rstd;
  AB[c]     = a;
  AB[C + c] = beta[c] - mean*a;
}

// ---------- GEMM1: LDS-tiled (64 rows/block), no register spill, in-place on Z ----------
__global__ __launch_bounds__(256, 4) void gemm1_kernel(float* __restrict__ Z,
                                                       const float* __restrict__ AB0,
                                                       const float* __restrict__ w1t,
                                                       const float* __restrict__ b1) {
  __shared__ float hs[64 * 129];           // stride 129: 2-way bank aliasing = free
  const int tid = threadIdx.x;
  const size_t base = (size_t)blockIdx.x * 64;

  const float4* Z4 = (const float4*)(Z + base * C);
#pragma unroll
  for (int k = 0; k < 8; ++k) {
    int f = tid + k*256;                   // float4 index, 0..2047
    int row = f >> 5, c4 = f & 31;
    float4 v  = Z4[f];
    float4 A  = ((const float4*)AB0)[c4];
    float4 Bb = ((const float4*)AB0)[32 + c4];
    int lb = row*129 + c4*4;
    hs[lb+0] = fmaxf(fmaf(v.x, A.x, Bb.x), 0.f);
    hs[lb+1] = fmaxf(fmaf(v.y, A.y, Bb.y), 0.f);
    hs[lb+2] = fmaxf(fmaf(v.z, A.z, Bb.z), 0.f);
    hs[lb+3] = fmaxf(fmaf(v.w, A.w, Bb.w), 0.f);
  }
  __syncthreads();

  const int row = tid & 63;
  const int qu  = __builtin_amdgcn_readfirstlane(tid >> 6);  // wave-uniform -> s_loads
  const float* wq = w1t + qu*32;           // w1t[c*C + o]
  float acc[32];
#pragma unroll
  for (int o = 0; o < 32; ++o) acc[o] = b1[qu*32 + o];
  const float* hrow = hs + row*129;
  for (int c = 0; c < C; ++c) {
    float x = hrow[c];
    const float* wr = wq + c*C;            // uniform: s_load_dwordx16 x2
#pragma unroll
    for (int o = 0; o < 32; ++o) acc[o] = fmaf(x, wr[o], acc[o]);
  }
  __syncthreads();

#pragma unroll
  for (int o = 0; o < 32; ++o) hs[row*129 + qu*32 + o] = acc[o];
  __syncthreads();
  float4* Zo = (float4*)(Z + base * C);
#pragma unroll
  for (int k = 0; k < 8; ++k) {
    int f = tid + k*256;
    int row2 = f >> 5, c4 = f & 31;
    int lb = row2*129 + c4*4;
    Zo[f] = make_float4(hs[lb+0], hs[lb+1], hs[lb+2], hs[lb+3]);
  }
}

// ---------- maxpool over K with BN1+ReLU fused ----------
__global__ void maxpool_kernel(const float* __restrict__ Z,
                               const float* __restrict__ AB1,
                               float* __restrict__ outF) {
  int t = blockIdx.x*256 + threadIdx.x;    // B*S*32
  int bs = t >> 5, c4 = t & 31;
  const float4* zp = (const float4*)Z + (size_t)bs*K*(C/4) + c4;
  float4 A  = ((const float4*)AB1)[c4];
  float4 Bb = ((const float4*)(AB1 + C))[c4];
  float4 m = make_float4(-3.4e38f, -3.4e38f, -3.4e38f, -3.4e38f);
#pragma unroll
  for (int k = 0; k < K; ++k) {
    float4 z = zp[(size_t)k*(C/4)];
    m.x = fmaxf(m.x, fmaf(z.x, A.x, Bb.x));
    m.y = fmaxf(m.y, fmaf(z.y, A.y, Bb.y));
    m.z = fmaxf(m.z, fmaf(z.z, A.z, Bb.z));
    m.w = fmaxf(m.w, fmaf(z.w, A.w, Bb.w));
  }
  m.x = fmaxf(m.x, 0.f); m.y = fmaxf(m.y, 0.f);
  m.z = fmaxf(m.z, 0.f); m.w = fmaxf(m.w, 0.f);
  ((float4*)outF)[t] = m;                  // max(relu(x)) == relu(max(x))
}

extern "C" void kernel_launch(void* const* d_in, const int* in_sizes, int n_in,
                              void* d_out, int out_size, void* d_ws, size_t ws_size,
                              hipStream_t stream) {
  const float* xyz      = (const float*)d_in[0];
  const float* features = (const float*)d_in[1];
  const float* w0  = (const float*)d_in[2];
  const float* b0  = (const float*)d_in[3];
  const float* g0  = (const float*)d_in[4];
  const float* be0 = (const float*)d_in[5];
  const float* w1  = (const float*)d_in[6];
  const float* b1  = (const float*)d_in[7];
  const float* g1  = (const float*)d_in[8];
  const float* be1 = (const float*)d_in[9];

  char* wp = (char*)d_ws;
  float4* pts4 = (float4*)wp;  wp += (size_t)B*N*sizeof(float4);     // 512 KB
  float4* q4   = (float4*)wp;  wp += (size_t)B*S*sizeof(float4);     // 128 KB
  float*  Z    = (float*)wp;   wp += (size_t)R*C*sizeof(float);      // 64 MB
  float*  part = (float*)wp;   wp += (size_t)128*C*2*sizeof(float);  // 128 KB
  float*  AB0  = (float*)wp;   wp += (size_t)2*C*sizeof(float);
  float*  AB1  = (float*)wp;   wp += (size_t)2*C*sizeof(float);
  float*  w1t  = (float*)wp;   wp += (size_t)C*C*sizeof(float);      // 64 KB
  float*  w0t  = (float*)wp;   wp += (size_t)67*C*sizeof(float);     // 34 KB
  unsigned* prog = (unsigned*)wp; wp += 4*sizeof(unsigned);          // progress counters

  float* out_xyz  = (float*)d_out;            // [B,S,3]
  float* out_feat = (float*)d_out + B*S*3;    // [B,S,C]

  prep_kernel<<<(B*N)/256, 256, 0, stream>>>(xyz, pts4, prog);
  transpose_w1_kernel<<<(C*C)/256, 256, 0, stream>>>(w1, w1t);
  transpose_w0_kernel<<<34, 256, 0, stream>>>(w0, w0t);
  // fused producer/consumer: 4 FPS blocks (512t) + 1024 consumer blocks (8 waves/query each)
  fps_knn_kernel<<<B + (B*S)/8, 512, 0, stream>>>(pts4, q4, out_xyz, features, w0t, b0, Z, prog);
  stats_kernel<<<128, 256, 0, stream>>>(Z, part);
  finalize_kernel<<<1, 128, 0, stream>>>(part, g0, be0, AB0);
  gemm1_kernel<<<R/64, 256, 0, stream>>>(Z, AB0, w1t, b1);
  stats_kernel<<<128, 256, 0, stream>>>(Z, part);
  finalize_kernel<<<1, 128, 0, stream>>>(part, g1, be1, AB1);
  maxpool_kernel<<<(B*S*32)/256, 256, 0, stream>>>(Z, AB1, out_feat);
}

// Round 13
// 1980.052 us; speedup vs baseline: 1.0391x; 1.0391x over previous
//
#include <hip/hip_runtime.h>

#define B 4
#define N 8192
#define F 64
#define S 2048
#define K 16
#define C 128
#define R (B*S*K)   // 131072 rows

typedef float v2f __attribute__((ext_vector_type(2)));

// ---------- exact-arithmetic helpers (match numpy op order, no fma fusion) ----------
__device__ __forceinline__ float norm2f(float x, float y, float z) {
#pragma clang fp contract(off)
  return (x*x + y*y) + z*z;
}

__device__ __forceinline__ float knn_d2(float4 q, float4 p) {
#pragma clang fp contract(off)
  float dot = (q.x*p.x + q.y*p.y) + q.z*p.z;
  return (q.w + p.w) - 2.0f*dot;           // (qn+pn) - 2*dot, reference order
}

// opaque def: forbids rematerialization of the value -> stays in a VGPR
__device__ __forceinline__ void pinf(float& v) { asm volatile("" : "+v"(v)); }

// ---------- DPP cross-lane (VALU pipe). bound_ctrl=1 -> invalid lanes read 0:
// identity-safe for u32/f32 max of non-negative values. HW-verified rounds 2-10.
#define DPP_U(v, ctrl) ((unsigned)__builtin_amdgcn_update_dpp(0, (int)(v), ctrl, 0xf, 0xf, true))
#define DPP_F(v, ctrl) __int_as_float((int)DPP_U(__float_as_uint(v), ctrl))
__device__ __forceinline__ unsigned umaxu(unsigned a, unsigned b) { return a > b ? a : b; }

#define WAVE_MAX_U(x) do { \
  x = umaxu(x, DPP_U(x,0x111)); x = umaxu(x, DPP_U(x,0x112)); \
  x = umaxu(x, DPP_U(x,0x114)); x = umaxu(x, DPP_U(x,0x118)); \
  x = umaxu(x, DPP_U(x,0x142)); x = umaxu(x, DPP_U(x,0x143)); } while(0)

// f32 max across wave into lane 63 (values >= 0; bound_ctrl 0-fill is identity-safe)
#define WAVE_MAX_F(x) do { \
  x = fmaxf(x, DPP_F(x,0x111)); x = fmaxf(x, DPP_F(x,0x112)); \
  x = fmaxf(x, DPP_F(x,0x114)); x = fmaxf(x, DPP_F(x,0x118)); \
  x = fmaxf(x, DPP_F(x,0x142)); x = fmaxf(x, DPP_F(x,0x143)); } while(0)

// ---------- prep: pad xyz to float4 with |p|^2 in w; zero progress counters ----------
__global__ void prep_kernel(const float* __restrict__ xyz, float4* __restrict__ pts4,
                            unsigned* __restrict__ prog) {
  int i = blockIdx.x*blockDim.x + threadIdx.x;   // B*N
  if (i < B) prog[i] = 0u;
  if (i >= B*N) return;
  float x = xyz[i*3+0], y = xyz[i*3+1], z = xyz[i*3+2];
  pts4[i] = make_float4(x, y, z, norm2f(x, y, z));
}

// ---------- transpose w1 [o][c] -> w1t [c][o] for contiguous scalar weight loads ----------
__global__ void transpose_w1_kernel(const float* __restrict__ w1, float* __restrict__ w1t) {
  int i = blockIdx.x*256 + threadIdx.x;    // C*C = 16384
  int o = i >> 7, c = i & 127;
  w1t[c*C + o] = w1[o*C + c];
}

// ---------- transpose w0 [o][67] -> w0t [67][o] for coalesced per-lane weight loads ----------
__global__ void transpose_w0_kernel(const float* __restrict__ w0, float* __restrict__ w0t) {
  int i = blockIdx.x*256 + threadIdx.x;    // 67*128 = 8576
  if (i >= 67*C) return;
  int c = i >> 7, o = i & 127;
  w0t[c*C + o] = w0[o*67 + c];
}

// ---------- FUSED FPS (blocks 0..3) + KNN+GEMM0 (blocks 4..2051, consumers).
// FINAL (r8 revert -- session best, 1982us verified). FPS: 256t (1 wave/SIMD),
// serial 2-chain argmax, f32+u32 DPP reduce, lane63 key -> parity LDS, ONE
// __syncthreads/step, 3x v_max_f64 tail. Occupancy/reduce/store variants all
// measured worse (ledger r0-r12): 256t=873ns/step floor; 512t=924; 1024t=1040;
// spin-poll 1300; ring/4-chain/tree neutral-to-negative. The step is bound by
// the serial chain {distance issue ~650cy, 2 dependent LDS round-trips ~240cy,
// 12 DPP stages ~100cy, barrier+skew} -- structural, not counter-roofline.
// Consumers: KNN then fused GEMM0 -- the wave holds the 16 neighbor ids in myg
// lanes 0..15 and computes its query's 16 Z rows directly (b0-init +
// ascending-c fmaf = bit-identical to the old gemm0 kernel). ----------
__global__ __launch_bounds__(256, 1) void fps_knn_kernel(const float4* __restrict__ pts4,
                                                         float4* __restrict__ q4,
                                                         float* __restrict__ out_xyz,
                                                         const float* __restrict__ feat,
                                                         const float* __restrict__ w0t,
                                                         const float* __restrict__ b0,
                                                         float* __restrict__ Z,
                                                         unsigned* __restrict__ prog) {
  __shared__ float4 cw[N];                 // 128 KB point cache (winner lookup, b128 read)
  __shared__ __align__(16) unsigned long long redarr[2][4];  // parity-buffered wave keys

  if (blockIdx.x < B) {
    // ================= FPS role =================
    const int b = blockIdx.x;
    const int t = threadIdx.x;
    const float4* pb = pts4 + b*N;

    // thread t owns points i*256+t, i=0..31, paired (2j, 2j+1); pinned in VGPRs
    v2f px[16], py[16], pz[16], md[16];
#pragma unroll
    for (int j = 0; j < 16; ++j) {
      int i0 = (2*j)*256 + t, i1 = (2*j+1)*256 + t;
      float4 v0 = pb[i0];                  // coalesced
      float4 v1 = pb[i1];
      cw[i0] = v0; cw[i1] = v1;
      pinf(v0.x); pinf(v0.y); pinf(v0.z);
      pinf(v1.x); pinf(v1.y); pinf(v1.z);
      px[j] = (v2f){v0.x, v1.x};
      py[j] = (v2f){v0.y, v1.y};
      pz[j] = (v2f){v0.z, v1.z};
      md[j] = (v2f){1e10f, 1e10f};         // BIG
    }
    __syncthreads();                       // cw visible before use

    float wx, wy, wz;
    { float4 p0 = pb[0]; wx = p0.x; wy = p0.y; wz = p0.z; }  // reference starts at idx 0

    for (int s = 0; ; ++s) {
      if (t == 0) {
        // publish BEFORE this step's store: fence only waits on >=1-step-old stores
        if ((s & 31) == 0 && s) {
          __threadfence();                 // order q4 stores before prog publish
          __hip_atomic_store(prog + b, (unsigned)s, __ATOMIC_RELAXED, __HIP_MEMORY_SCOPE_AGENT);
        }
        float w2 = norm2f(wx, wy, wz);
        q4[b*S + s] = make_float4(wx, wy, wz, w2);
      }
      if (s == S-1) break;

      // packed min_d update + two independent argmax chains (slots 0..15 / 16..31).
      // per-element IEEE rounding identical to scalar ((dx*dx+dy*dy)+dz*dz).
      v2f wxx = (v2f){wx, wx}, wyy = (v2f){wy, wy}, wzz = (v2f){wz, wz};
      float bvA = -1.0f, bvB = -1.0f; int biA = 0, biB = 0;
#pragma unroll
      for (int j = 0; j < 16; ++j) {
#pragma clang fp contract(off)
        v2f dx = px[j] - wxx;
        v2f dy = py[j] - wyy;
        v2f dz = pz[j] - wzz;
        v2f d  = (dx*dx + dy*dy) + dz*dz;  // v_pk/scalar sub-mul-add, no fma
        v2f m;
        m.x = fminf(md[j].x, d.x);
        m.y = fminf(md[j].y, d.y);
        md[j] = m;
        if (j < 8) {                       // chain A: slots 0..15
          bool g0 = m.x > bvA;  bvA = g0 ? m.x : bvA;  biA = g0 ? (2*j)   : biA;
          bool g1 = m.y > bvA;  bvA = g1 ? m.y : bvA;  biA = g1 ? (2*j+1) : biA;
        } else {                           // chain B: slots 16..31
          bool g0 = m.x > bvB;  bvB = g0 ? m.x : bvB;  biB = g0 ? (2*j)   : biB;
          bool g1 = m.y > bvB;  bvB = g1 ? m.y : bvB;  biB = g1 ? (2*j+1) : biB;
        }
      }
      // merge chains: strict > keeps A (lower slots = lower global idx) on ties
      bool gB = bvB > bvA;
      float bv = gB ? bvB : bvA;           // bv >= 0 always (set at j=0 / j=8)
      int   bi = gB ? biB : biA;

      // ---- two-stage wave reduce: f32 value max, then min-original-idx among ties
      float v = bv;
      WAVE_MAX_F(v);                       // lane 63 holds wave max value
      float wmaxv = __int_as_float(__builtin_amdgcn_readlane(__float_as_int(v), 63));
      unsigned loi = 8191u - (((unsigned)bi << 8) + (unsigned)t);  // bigger = smaller oi
      unsigned tmp = (bv == wmaxv) ? loi : 0u;
      WAVE_MAX_U(tmp);                     // lane 63: max loi among value-ties
      if ((t & 63) == 63)
        redarr[s & 1][t >> 6] = ((unsigned long long)__float_as_uint(wmaxv) << 32)
                              | (unsigned long long)tmp;
      __syncthreads();                     // single barrier/step; writes ordered by it

      // global best of 4 wave keys: positive u64 patterns order as f64 -> 3x v_max_f64
      const unsigned long long* ra = redarr[s & 1];
      double k0 = __longlong_as_double((long long)ra[0]);
      double k1 = __longlong_as_double((long long)ra[1]);
      double k2 = __longlong_as_double((long long)ra[2]);
      double k3 = __longlong_as_double((long long)ra[3]);
      double g  = fmax(fmax(k0, k1), fmax(k2, k3));
      unsigned long long gb = (unsigned long long)__double_as_longlong(g);
      int w = 8191 - (int)((unsigned)gb & 0x1FFFu); // winner original index
      float4 pw = cw[w];                   // one same-address ds_read_b128 broadcast
      wx = pw.x; wy = pw.y; wz = pw.z;
    }
    if (t == 0) {                          // final publish covers tail (incl. s=S-1)
      __threadfence();                     // drains all q4 stores (vmcnt 0)
      __hip_atomic_store(prog + b, (unsigned)S, __ATOMIC_RELAXED, __HIP_MEMORY_SCOPE_AGENT);
    }
    __syncthreads();                       // t0's drain done -> q4 fully visible in L2
    // out_xyz write-back off the critical path (q4 is L2-hot)
    for (int i = t; i < S; i += 256) {
      float4 v = q4[b*S + i];
      out_xyz[(b*S + i)*3 + 0] = v.x;
      out_xyz[(b*S + i)*3 + 1] = v.y;
      out_xyz[(b*S + i)*3 + 2] = v.z;
    }
  } else {
    // ================= consumer role: one WAVE per query (KNN + GEMM0) =================
    const int qw   = (blockIdx.x - B)*4 + (threadIdx.x >> 6);  // 0..B*S-1
    const int lane = threadIdx.x & 63;
    const int b    = qw & 3;               // interleave batches: earliest queries first
    const int s    = qw >> 2;
    const int bs   = b*S + s;
    const float4* pb = pts4 + (size_t)b*N;

    // spin until query s of batch b is published (prog jumps in steps of 32)
    while (__hip_atomic_load(prog + b, __ATOMIC_RELAXED, __HIP_MEMORY_SCOPE_AGENT) <= (unsigned)s)
      __builtin_amdgcn_s_sleep(64);
    __threadfence();                       // acquire: order prog read before q4 read

    float4 q = q4[bs];                     // same addr across wave -> broadcast

    float dv[16]; int di[16];
#pragma unroll
    for (int j = 0; j < 16; ++j) { dv[j] = 3.4e38f; di[j] = 0x7FFFFFFF; }

    // scan: lane owns points n = j*64 + lane (ascending -> within-lane ties keep lower idx)
    for (int j = 0; j < N/64; ++j) {
      int n = j*64 + lane;
      float4 p = pb[n];                    // coalesced global_load_dwordx4
      float d2 = knn_d2(q, p);
#pragma unroll
      for (int k = 15; k >= 1; --k) {
        bool s1 = d2 < dv[k-1];            // strict: incumbent (earlier idx) wins ties
        bool s2 = d2 < dv[k];
        dv[k] = fmaxf(dv[k-1], fminf(d2, dv[k]));   // med3: sorted-insert value update
        di[k] = s1 ? di[k-1] : (s2 ? n : di[k]);
      }
      bool s0 = d2 < dv[0];
      dv[0] = fminf(d2, dv[0]);
      di[0] = s0 ? n : di[0];
    }

    // merge: 16 extraction rounds over the 64 sorted lane-lists
    int myg = 0;
#pragma unroll 1
    for (int r = 0; r < 16; ++r) {
      unsigned bits = __float_as_uint(dv[0]);
      unsigned ord  = bits ^ (0x80000000u | (unsigned)(((int)bits) >> 31));
      unsigned mk   = ~ord;                // max(mk) == min distance (total order)
      unsigned m = mk;
      WAVE_MAX_U(m);
      unsigned wm = (unsigned)__builtin_amdgcn_readlane((int)m, 63);
      unsigned ci = (mk == wm) ? ~(unsigned)di[0] : 0u;
      unsigned m2 = ci;
      WAVE_MAX_U(m2);
      unsigned wi = (unsigned)__builtin_amdgcn_readlane((int)m2, 63);
      int g = (int)~wi;                    // winning global point index
      if (lane == r) myg = g;
      bool win = (mk == wm) && ((unsigned)di[0] == ~wi);
#pragma unroll
      for (int k = 0; k < 15; ++k) {
        dv[k] = win ? dv[k+1] : dv[k];
        di[k] = win ? di[k+1] : di[k];
      }
      dv[15] = win ? 3.4e38f    : dv[15];
      di[15] = win ? 0x7FFFFFFF : di[15];
    }

    // ---- fused GEMM0: this wave computes its query's 16 rows of Z.
    // lane owns outputs o0 and o0+64; per output: b0-init + ascending-c fmaf
    // (bit-identical accumulation order to the old gemm0 kernel).
    const int o0 = lane;
    const float bb0 = b0[o0];              // coalesced
    const float bb1 = b0[o0 + 64];
    const float* w0c = w0t + o0;           // w0t[c*C + o]
    float* zb = Z + (size_t)bs*K*C;
#pragma unroll 1
    for (int k = 0; k < K; ++k) {
      int p = __builtin_amdgcn_readlane(myg, k);   // neighbor id (uniform)
      float4 pp = pts4[(size_t)b*N + p];           // uniform addr -> broadcast
      float a0 = bb0, a1 = bb1;
      float x0 = pp.x - q.x, x1 = pp.y - q.y, x2 = pp.z - q.z;
      a0 = fmaf(x0, w0c[0*C],      a0); a1 = fmaf(x0, w0c[0*C + 64], a1);
      a0 = fmaf(x1, w0c[1*C],      a0); a1 = fmaf(x1, w0c[1*C + 64], a1);
      a0 = fmaf(x2, w0c[2*C],      a0); a1 = fmaf(x2, w0c[2*C + 64], a1);
      const float4* fp = (const float4*)(feat + ((size_t)b*N + p)*F);
#pragma unroll
      for (int i = 0; i < 16; ++i) {
        float4 vv = fp[i];                 // uniform addr -> broadcast
        const float* wc = w0c + (3 + 4*i)*C;
        a0 = fmaf(vv.x, wc[0*C], a0); a1 = fmaf(vv.x, wc[0*C + 64], a1);
        a0 = fmaf(vv.y, wc[1*C], a0); a1 = fmaf(vv.y, wc[1*C + 64], a1);
        a0 = fmaf(vv.z, wc[2*C], a0); a1 = fmaf(vv.z, wc[2*C + 64], a1);
        a0 = fmaf(vv.w, wc[3*C], a0); a1 = fmaf(vv.w, wc[3*C + 64], a1);
      }
      zb[k*C + o0]      = a0;              // coalesced
      zb[k*C + o0 + 64] = a1;
    }
  }
}

// ---------- per-channel stats partials: sum and sumsq over rows ----------
__global__ void stats_kernel(const float* __restrict__ Z, float* __restrict__ part) {
  int c = threadIdx.x & 127;
  int g = threadIdx.x >> 7;                // 0/1
  int chunk = blockIdx.x*2 + g;            // 0..255
  const int rows = R/256;                  // 512
  const float* zp = Z + (size_t)chunk*rows*C + c;
  float s1 = 0.f, s2 = 0.f;
  for (int j = 0; j < rows; ++j) {
    float v = zp[(size_t)j*C];
    s1 += v;
    s2 = fmaf(v, v, s2);
  }
  __shared__ float sh[2][2][128];
  sh[g][0][c] = s1; sh[g][1][c] = s2;
  __syncthreads();
  if (g == 0) {
    part[(blockIdx.x*128 + c)*2 + 0] = s1 + sh[1][0][c];
    part[(blockIdx.x*128 + c)*2 + 1] = s2 + sh[1][1][c];
  }
}

// ---------- finalize BN: A = gamma*rstd, B = beta - mean*gamma*rstd ----------
__global__ void finalize_kernel(const float* __restrict__ part,
                                const float* __restrict__ gamma,
                                const float* __restrict__ beta,
                                float* __restrict__ AB) {
  int c = threadIdx.x;                     // 128 threads
  float s1 = 0.f, s2 = 0.f;
  for (int i = 0; i < 128; ++i) {
    s1 += part[(i*128 + c)*2 + 0];
    s2 += part[(i*128 + c)*2 + 1];
  }
  const float inv = 1.0f/(float)R;
  float mean = s1*inv;
  float var  = s2*inv - mean*mean;         // biased variance
  float rstd = rsqrtf(var + 1e-5f);
  float a = gamma[c]*rstd;
  AB[c]     = a;
  AB[C + c] = beta[c] - mean*a;
}

// ---------- GEMM1: LDS-tiled (64 rows/block), no register spill, in-place on Z ----------
__global__ __launch_bounds__(256, 4) void gemm1_kernel(float* __restrict__ Z,
                                                       const float* __restrict__ AB0,
                                                       const float* __restrict__ w1t,
                                                       const float* __restrict__ b1) {
  __shared__ float hs[64 * 129];           // stride 129: 2-way bank aliasing = free
  const int tid = threadIdx.x;
  const size_t base = (size_t)blockIdx.x * 64;

  const float4* Z4 = (const float4*)(Z + base * C);
#pragma unroll
  for (int k = 0; k < 8; ++k) {
    int f = tid + k*256;                   // float4 index, 0..2047
    int row = f >> 5, c4 = f & 31;
    float4 v  = Z4[f];
    float4 A  = ((const float4*)AB0)[c4];
    float4 Bb = ((const float4*)AB0)[32 + c4];
    int lb = row*129 + c4*4;
    hs[lb+0] = fmaxf(fmaf(v.x, A.x, Bb.x), 0.f);
    hs[lb+1] = fmaxf(fmaf(v.y, A.y, Bb.y), 0.f);
    hs[lb+2] = fmaxf(fmaf(v.z, A.z, Bb.z), 0.f);
    hs[lb+3] = fmaxf(fmaf(v.w, A.w, Bb.w), 0.f);
  }
  __syncthreads();

  const int row = tid & 63;
  const int qu  = __builtin_amdgcn_readfirstlane(tid >> 6);  // wave-uniform -> s_loads
  const float* wq = w1t + qu*32;           // w1t[c*C + o]
  float acc[32];
#pragma unroll
  for (int o = 0; o < 32; ++o) acc[o] = b1[qu*32 + o];
  const float* hrow = hs + row*129;
  for (int c = 0; c < C; ++c) {
    float x = hrow[c];
    const float* wr = wq + c*C;            // uniform: s_load_dwordx16 x2
#pragma unroll
    for (int o = 0; o < 32; ++o) acc[o] = fmaf(x, wr[o], acc[o]);
  }
  __syncthreads();

#pragma unroll
  for (int o = 0; o < 32; ++o) hs[row*129 + qu*32 + o] = acc[o];
  __syncthreads();
  float4* Zo = (float4*)(Z + base * C);
#pragma unroll
  for (int k = 0; k < 8; ++k) {
    int f = tid + k*256;
    int row2 = f >> 5, c4 = f & 31;
    int lb = row2*129 + c4*4;
    Zo[f] = make_float4(hs[lb+0], hs[lb+1], hs[lb+2], hs[lb+3]);
  }
}

// ---------- maxpool over K with BN1+ReLU fused ----------
__global__ void maxpool_kernel(const float* __restrict__ Z,
                               const float* __restrict__ AB1,
                               float* __restrict__ outF) {
  int t = blockIdx.x*256 + threadIdx.x;    // B*S*32
  int bs = t >> 5, c4 = t & 31;
  const float4* zp = (const float4*)Z + (size_t)bs*K*(C/4) + c4;
  float4 A  = ((const float4*)AB1)[c4];
  float4 Bb = ((const float4*)(AB1 + C))[c4];
  float4 m = make_float4(-3.4e38f, -3.4e38f, -3.4e38f, -3.4e38f);
#pragma unroll
  for (int k = 0; k < K; ++k) {
    float4 z = zp[(size_t)k*(C/4)];
    m.x = fmaxf(m.x, fmaf(z.x, A.x, Bb.x));
    m.y = fmaxf(m.y, fmaf(z.y, A.y, Bb.y));
    m.z = fmaxf(m.z, fmaf(z.z, A.z, Bb.z));
    m.w = fmaxf(m.w, fmaf(z.w, A.w, Bb.w));
  }
  m.x = fmaxf(m.x, 0.f); m.y = fmaxf(m.y, 0.f);
  m.z = fmaxf(m.z, 0.f); m.w = fmaxf(m.w, 0.f);
  ((float4*)outF)[t] = m;                  // max(relu(x)) == relu(max(x))
}

extern "C" void kernel_launch(void* const* d_in, const int* in_sizes, int n_in,
                              void* d_out, int out_size, void* d_ws, size_t ws_size,
                              hipStream_t stream) {
  const float* xyz      = (const float*)d_in[0];
  const float* features = (const float*)d_in[1];
  const float* w0  = (const float*)d_in[2];
  const float* b0  = (const float*)d_in[3];
  const float* g0  = (const float*)d_in[4];
  const float* be0 = (const float*)d_in[5];
  const float* w1  = (const float*)d_in[6];
  const float* b1  = (const float*)d_in[7];
  const float* g1  = (const float*)d_in[8];
  const float* be1 = (const float*)d_in[9];

  char* wp = (char*)d_ws;
  float4* pts4 = (float4*)wp;  wp += (size_t)B*N*sizeof(float4);     // 512 KB
  float4* q4   = (float4*)wp;  wp += (size_t)B*S*sizeof(float4);     // 128 KB
  float*  Z    = (float*)wp;   wp += (size_t)R*C*sizeof(float);      // 64 MB
  float*  part = (float*)wp;   wp += (size_t)128*C*2*sizeof(float);  // 128 KB
  float*  AB0  = (float*)wp;   wp += (size_t)2*C*sizeof(float);
  float*  AB1  = (float*)wp;   wp += (size_t)2*C*sizeof(float);
  float*  w1t  = (float*)wp;   wp += (size_t)C*C*sizeof(float);      // 64 KB
  float*  w0t  = (float*)wp;   wp += (size_t)67*C*sizeof(float);     // 34 KB
  unsigned* prog = (unsigned*)wp; wp += 4*sizeof(unsigned);          // progress counters

  float* out_xyz  = (float*)d_out;            // [B,S,3]
  float* out_feat = (float*)d_out + B*S*3;    // [B,S,C]

  prep_kernel<<<(B*N)/256, 256, 0, stream>>>(xyz, pts4, prog);
  transpose_w1_kernel<<<(C*C)/256, 256, 0, stream>>>(w1, w1t);
  transpose_w0_kernel<<<34, 256, 0, stream>>>(w0, w0t);
  // fused producer/consumer: 4 FPS blocks + 2048 consumer blocks (KNN+GEMM0, one wave/query)
  fps_knn_kernel<<<B + (B*S)/4, 256, 0, stream>>>(pts4, q4, out_xyz, features, w0t, b0, Z, prog);
  stats_kernel<<<128, 256, 0, stream>>>(Z, part);
  finalize_kernel<<<1, 128, 0, stream>>>(part, g0, be0, AB0);
  gemm1_kernel<<<R/64, 256, 0, stream>>>(Z, AB0, w1t, b1);
  stats_kernel<<<128, 256, 0, stream>>>(Z, part);
  finalize_kernel<<<1, 128, 0, stream>>>(part, g1, be1, AB1);
  maxpool_kernel<<<(B*S*32)/256, 256, 0, stream>>>(Z, AB1, out_feat);
}